// Round 1
// baseline (243.380 us; speedup 1.0000x reference)
//
#include <hip/hip_runtime.h>
#include <hip/hip_fp16.h>
#include <math.h>

// ---------------------------------------------------------------------------
// AttentionZP: swishmax attention, B=2, H=8, T=1024, A=64, C=256, Q=K=2048.
//
// Pipeline (all on `stream`):
//   1. ew_split:        tokens fp32 -> bf16 hi/lo (+ fp16 copy for key tokens)
//   2. transpose_split: weights fp32 -> transposed bf16 hi/lo (Wq,Wk) / fp16 (Wv_down, Wv_up)
//   3. proj_gemm:       q = Qtok*Wq + bias, k = Ktok*Wk   (split-bf16 3-term MFMA, out hi|lo)
//   4. kv_gemm:         kvT[bh][c][key] = (Ktok*Wv_down)^T (fp16 MFMA)
//   5. flash_attn:      per (b,h,64-q-block): online swishmax over keys, acc = attn^T*kv
//   6. final_gemm:      out[b,q,t] = vs_c[b,q,(h,c)] * vupT[(h,c)->t]  (fp16, head-sum in K)
//
// Numerics: logits path in split-bf16 (hi+lo => ~2^-17 product error, exp-safe);
// value path in fp16. Swishmax denom has +1 => NOT max-shift invariant, so the
// flash loop keeps true max m_true alongside deferred working max m_cur and
// applies an exact final fixup.
// ---------------------------------------------------------------------------

typedef _Float16 f16;
typedef _Float16 f16x4 __attribute__((ext_vector_type(4)));
typedef _Float16 f16x8 __attribute__((ext_vector_type(8)));
typedef short s16x4 __attribute__((ext_vector_type(4)));
typedef short bf16x8 __attribute__((ext_vector_type(8)));
typedef float f32x4 __attribute__((ext_vector_type(4)));

#define MFMA_F16(a, b, c) __builtin_amdgcn_mfma_f32_16x16x32_f16(a, b, c, 0, 0, 0)
#define MFMA_BF16(a, b, c) __builtin_amdgcn_mfma_f32_16x16x32_bf16(a, b, c, 0, 0, 0)

__device__ __forceinline__ void g2lds16(const void* g, void* l) {
  // async global->LDS, 16B/lane; LDS dest is wave-uniform base + lane*16
  __builtin_amdgcn_global_load_lds((__attribute__((address_space(1))) void*)g,
                                   (__attribute__((address_space(3))) void*)l, 16, 0, 0);
}

__device__ __forceinline__ short f32_bf16(float x) {
  union { float f; unsigned u; } v; v.f = x;
  unsigned r = v.u + 0x7FFFu + ((v.u >> 16) & 1u);  // RTN-even
  return (short)(r >> 16);
}
__device__ __forceinline__ float bf16_f32(short h) {
  union { unsigned u; float f; } v; v.u = ((unsigned)(unsigned short)h) << 16;
  return v.f;
}

// --------------------------- prep: elementwise split ------------------------
__global__ __launch_bounds__(256) void ew_split(const float* __restrict__ in,
                                                short* __restrict__ bhi,
                                                short* __restrict__ blo,
                                                f16* __restrict__ fo, int n4) {
  int i = blockIdx.x * 256 + threadIdx.x;
  int stride = gridDim.x * 256;
  for (; i < n4; i += stride) {
    f32x4 v = ((const f32x4*)in)[i];
    s16x4 h, l;
    f16x4 f;
#pragma unroll
    for (int j = 0; j < 4; j++) {
      short hj = f32_bf16(v[j]);
      h[j] = hj;
      l[j] = f32_bf16(v[j] - bf16_f32(hj));
      f[j] = (f16)v[j];
    }
    ((s16x4*)bhi)[i] = h;
    ((s16x4*)blo)[i] = l;
    if (fo) ((f16x4*)fo)[i] = f;
  }
}

// --------------------------- prep: transpose (+split) -----------------------
// in: [batch][R][C] f32 -> out: [batch][C][R]  (bf16 hi/lo and/or f16)
__global__ __launch_bounds__(256) void transpose_split(const float* __restrict__ in,
                                                       short* __restrict__ bhi,
                                                       short* __restrict__ blo,
                                                       f16* __restrict__ fo,
                                                       int R, int C) {
  __shared__ float t[64][65];
  int cb = blockIdx.x * 64, rb = blockIdx.y * 64;
  size_t batch = (size_t)blockIdx.z * R * C;
  int tid = threadIdx.x;
#pragma unroll
  for (int i = 0; i < 4; i++) {
    int r = (tid >> 4) + i * 16, c4 = (tid & 15) * 4;
    f32x4 v = *(const f32x4*)(in + batch + (size_t)(rb + r) * C + cb + c4);
    t[r][c4] = v[0]; t[r][c4 + 1] = v[1]; t[r][c4 + 2] = v[2]; t[r][c4 + 3] = v[3];
  }
  __syncthreads();
#pragma unroll
  for (int i = 0; i < 4; i++) {
    int c = (tid >> 4) + i * 16, r4 = (tid & 15) * 4;
    float v0 = t[r4][c], v1 = t[r4 + 1][c], v2 = t[r4 + 2][c], v3 = t[r4 + 3][c];
    size_t o = batch + (size_t)(cb + c) * R + rb + r4;
    if (bhi) {
      s16x4 h = {f32_bf16(v0), f32_bf16(v1), f32_bf16(v2), f32_bf16(v3)};
      *(s16x4*)(bhi + o) = h;
      s16x4 l = {f32_bf16(v0 - bf16_f32(h[0])), f32_bf16(v1 - bf16_f32(h[1])),
                 f32_bf16(v2 - bf16_f32(h[2])), f32_bf16(v3 - bf16_f32(h[3]))};
      *(s16x4*)(blo + o) = l;
    }
    if (fo) {
      f16x4 fv = {(f16)v0, (f16)v1, (f16)v2, (f16)v3};
      *(f16x4*)(fo + o) = fv;
    }
  }
}

// --------------------------- split-bf16 projection GEMM ----------------------
// M=4096(b,row) K=1024(t) N=512(h,a).  A=[4096][1024] hi/lo, B(T)=[512][1024] hi/lo.
// out: {q,k}_split[bh][row][ hi(64) | lo(64) ]  (bf16)
__global__ __launch_bounds__(256, 2) void proj_gemm(
    const short* __restrict__ qtok_hi, const short* __restrict__ qtok_lo,
    const short* __restrict__ ktok_hi, const short* __restrict__ ktok_lo,
    const short* __restrict__ wqT_hi, const short* __restrict__ wqT_lo,
    const short* __restrict__ wkT_hi, const short* __restrict__ wkT_lo,
    const float* __restrict__ bias, short* __restrict__ q_split,
    short* __restrict__ k_split) {
  const bool isQ = (blockIdx.z == 0);
  const short* Ahi = isQ ? qtok_hi : ktok_hi;
  const short* Alo = isQ ? qtok_lo : ktok_lo;
  const short* Bhi = isQ ? wqT_hi : wkT_hi;
  const short* Blo = isQ ? wqT_lo : wkT_lo;
  short* outp = isQ ? q_split : k_split;

  __shared__ __attribute__((aligned(16))) short sm[4][128 * 32];

  int tid = threadIdx.x, w = tid >> 6, lane = tid & 63, g = lane >> 4, li = lane & 15;
  int mb = blockIdx.y * 128, nb = blockIdx.x * 128;
  int wm = (w >> 1) * 64, wn = (w & 1) * 64;

  f32x4 acc[4][4] = {};

  for (int kb = 0; kb < 1024; kb += 32) {
    __syncthreads();
#pragma unroll
    for (int i = 0; i < 2; i++) {
      int off = (w * 2 + i) * 1024 + lane * 16;  // bytes within 8KB tile
      int row = off >> 6;
      int ss = ((off >> 4) & 3) ^ ((row >> 1) & 3);  // XOR swizzle, 64B rows
      size_t asrc = (size_t)(mb + row) * 1024 + kb + ss * 8;
      size_t bsrc = (size_t)(nb + row) * 1024 + kb + ss * 8;
      int dst = (w * 2 + i) * 512;  // halfs
      g2lds16(Ahi + asrc, &sm[0][dst]);
      g2lds16(Alo + asrc, &sm[1][dst]);
      g2lds16(Bhi + bsrc, &sm[2][dst]);
      g2lds16(Blo + bsrc, &sm[3][dst]);
    }
    __syncthreads();
    bf16x8 af[4][2], bf[4][2];
#pragma unroll
    for (int f = 0; f < 4; f++) {
      int ra = wm + f * 16 + li;
      int sa = g ^ ((ra >> 1) & 3);
      af[f][0] = *(const bf16x8*)&sm[0][ra * 32 + sa * 8];
      af[f][1] = *(const bf16x8*)&sm[1][ra * 32 + sa * 8];
      int rb = wn + f * 16 + li;
      int sb = g ^ ((rb >> 1) & 3);
      bf[f][0] = *(const bf16x8*)&sm[2][rb * 32 + sb * 8];
      bf[f][1] = *(const bf16x8*)&sm[3][rb * 32 + sb * 8];
    }
#pragma unroll
    for (int mf = 0; mf < 4; mf++)
#pragma unroll
      for (int nf = 0; nf < 4; nf++) {
        acc[mf][nf] = MFMA_BF16(af[mf][0], bf[nf][0], acc[mf][nf]);
        acc[mf][nf] = MFMA_BF16(af[mf][0], bf[nf][1], acc[mf][nf]);
        acc[mf][nf] = MFMA_BF16(af[mf][1], bf[nf][0], acc[mf][nf]);
      }
  }
#pragma unroll
  for (int mf = 0; mf < 4; mf++)
#pragma unroll
    for (int nf = 0; nf < 4; nf++)
#pragma unroll
      for (int r = 0; r < 4; r++) {
        int m = mb + wm + mf * 16 + 4 * g + r;
        int n = nb + wn + nf * 16 + li;
        float v = acc[mf][nf][r];
        if (isQ) v += bias[n];
        short hi = f32_bf16(v);
        short lo = f32_bf16(v - bf16_f32(hi));
        size_t base = ((size_t)((m >> 11) * 8 + (n >> 6)) * 2048 + (m & 2047)) * 128;
        outp[base + (n & 63)] = hi;
        outp[base + 64 + (n & 63)] = lo;
      }
}

// --------------------------- fp16 kv GEMM (writes kv transposed) ------------
// M=4096(key rows) K=1024(t) N=2048(h,c). out kvT[bh][c][key] f16.
__global__ __launch_bounds__(256, 2) void kv_gemm(const f16* __restrict__ A,
                                                  const f16* __restrict__ Bm,
                                                  f16* __restrict__ kvT) {
  __shared__ __attribute__((aligned(16))) f16 sm[2][128 * 32];
  int tid = threadIdx.x, w = tid >> 6, lane = tid & 63, g = lane >> 4, li = lane & 15;
  int mb = blockIdx.y * 128, nb = blockIdx.x * 128;
  int wm = (w >> 1) * 64, wn = (w & 1) * 64;
  f32x4 acc[4][4] = {};
  for (int kb = 0; kb < 1024; kb += 32) {
    __syncthreads();
#pragma unroll
    for (int i = 0; i < 2; i++) {
      int off = (w * 2 + i) * 1024 + lane * 16;
      int row = off >> 6;
      int ss = ((off >> 4) & 3) ^ ((row >> 1) & 3);
      int dst = (w * 2 + i) * 512;
      g2lds16(A + (size_t)(mb + row) * 1024 + kb + ss * 8, &sm[0][dst]);
      g2lds16(Bm + (size_t)(nb + row) * 1024 + kb + ss * 8, &sm[1][dst]);
    }
    __syncthreads();
    f16x8 af[4], bf[4];
#pragma unroll
    for (int f = 0; f < 4; f++) {
      int ra = wm + f * 16 + li;
      int sa = g ^ ((ra >> 1) & 3);
      af[f] = *(const f16x8*)&sm[0][ra * 32 + sa * 8];
      int rb = wn + f * 16 + li;
      int sb = g ^ ((rb >> 1) & 3);
      bf[f] = *(const f16x8*)&sm[1][rb * 32 + sb * 8];
    }
#pragma unroll
    for (int mf = 0; mf < 4; mf++)
#pragma unroll
      for (int nf = 0; nf < 4; nf++)
        acc[mf][nf] = MFMA_F16(af[mf], bf[nf], acc[mf][nf]);
  }
#pragma unroll
  for (int mf = 0; mf < 4; mf++)
#pragma unroll
    for (int nf = 0; nf < 4; nf++) {
      int m = mb + wm + mf * 16 + 4 * g;  // 4 consecutive keys in regs 0..3
      int n = nb + wn + nf * 16 + li;     // (h<<8)|c
      f16x4 v = {(f16)acc[mf][nf][0], (f16)acc[mf][nf][1], (f16)acc[mf][nf][2],
                 (f16)acc[mf][nf][3]};
      size_t o = ((size_t)((m >> 11) * 8 + (n >> 8)) * 256 + (n & 255)) * 2048 + (m & 2047);
      *(f16x4*)(kvT + o) = v;
    }
}

// --------------------------- flash swishmax attention ------------------------
// grid 512: XCD-swizzled (bh pair per XCD). Block: 64 q rows, 4 waves x 16 q.
// Per 32-key tile: S^T[k,q]=mfma(K,Q) split-bf16; online swishmax (deferred max,
// true max tracked); P -> fp16 via wave-private LDS; acc[c,q] += mfma(kvT, P^T).
__global__ __launch_bounds__(256, 2) void flash_attn(const short* __restrict__ q_split,
                                                     const short* __restrict__ k_split,
                                                     const f16* __restrict__ kvT,
                                                     f16* __restrict__ vs_c) {
  __shared__ __attribute__((aligned(16))) short k_lds[32 * 128];  // 8KB  (hi|lo rows)
  __shared__ __attribute__((aligned(16))) f16 kv_lds[256 * 32];   // 16KB (c-major)
  __shared__ __attribute__((aligned(16))) f16 p_lds[4][640];      // wave-private P

  const int bid = blockIdx.x;
  const int bh = ((bid & 7) << 1) + ((bid >> 3) & 1);  // 2 bh per XCD for L2 reuse
  const int qb = bid >> 4;
  const int tid = threadIdx.x;
  const int w = tid >> 6, lane = tid & 63, g = lane >> 4, li = lane & 15;

  // Q fragments (persist whole kernel): B-operand, lane holds its q-row's a-slice
  const short* qrow = q_split + ((size_t)bh * 2048 + qb * 64 + w * 16 + li) * 128;
  bf16x8 qf[2][2];
#pragma unroll
  for (int ach = 0; ach < 2; ach++)
#pragma unroll
    for (int hl = 0; hl < 2; hl++)
      qf[ach][hl] = *(const bf16x8*)(qrow + hl * 64 + ach * 32 + g * 8);

  const short* kbase = k_split + (size_t)bh * 2048 * 128;
  const f16* kvbase = kvT + (size_t)bh * 256 * 2048;

  float m_cur = -INFINITY, m_true = -INFINITY, l_run = 0.f;
  f32x4 acc[16] = {};

  for (int kt = 0; kt < 64; kt++) {
    __syncthreads();
    // stage K tile [32][128] (256B rows, 16 slots, swz slot^(row&7))
#pragma unroll
    for (int i = 0; i < 2; i++) {
      int off = (w * 2 + i) * 1024 + lane * 16;
      int row = off >> 8;
      int ss = ((off >> 4) & 15) ^ (row & 7);
      g2lds16(kbase + (size_t)(kt * 32 + row) * 128 + ss * 8,
              (char*)k_lds + (w * 2 + i) * 1024);
    }
    // stage kvT tile [256][32] (64B rows, 4 slots, swz slot^((c>>1)&3))
#pragma unroll
    for (int i = 0; i < 4; i++) {
      int off = (w * 4 + i) * 1024 + lane * 16;
      int c = off >> 6;
      int ss = ((off >> 4) & 3) ^ ((c >> 1) & 3);
      g2lds16(kvbase + (size_t)c * 2048 + kt * 32 + ss * 8,
              (char*)kv_lds + (w * 4 + i) * 1024);
    }
    __syncthreads();

    // S^T[k, q] over 32 keys x this wave's 16 q
    f32x4 s[2] = {};
#pragma unroll
    for (int kc = 0; kc < 2; kc++) {
      const int r = kc * 16 + li;
#pragma unroll
      for (int ach = 0; ach < 2; ach++) {
        int sh = (ach * 4 + g) ^ (r & 7);
        int sl = (8 + ach * 4 + g) ^ (r & 7);
        bf16x8 khi = *(const bf16x8*)((const char*)k_lds + r * 256 + sh * 16);
        bf16x8 klo = *(const bf16x8*)((const char*)k_lds + r * 256 + sl * 16);
        s[kc] = MFMA_BF16(khi, qf[ach][0], s[kc]);
        s[kc] = MFMA_BF16(khi, qf[ach][1], s[kc]);
        s[kc] = MFMA_BF16(klo, qf[ach][0], s[kc]);
      }
    }

    // online swishmax; lane's q = li, its 8 S values span 8 keys
    float tmax = fmaxf(fmaxf(fmaxf(s[0][0], s[0][1]), fmaxf(s[0][2], s[0][3])),
                       fmaxf(fmaxf(s[1][0], s[1][1]), fmaxf(s[1][2], s[1][3])));
    tmax = fmaxf(tmax, __shfl_xor(tmax, 16));
    tmax = fmaxf(tmax, __shfl_xor(tmax, 32));
    m_true = fmaxf(m_true, tmax);
    if (__any(tmax > m_cur + 4.0f)) {  // deferred rescale; P bounded by ~117*e^4 < f16 max
      float mn = fmaxf(m_cur, tmax);
      float sc = __expf(m_cur - mn);  // first iter: exp(-inf)=0, acc already 0
      l_run *= sc;
#pragma unroll
      for (int i = 0; i < 16; i++) acc[i] *= sc;
      m_cur = mn;
    }
    float ls = 0.f;
    float pv[8];
#pragma unroll
    for (int kc = 0; kc < 2; kc++)
#pragma unroll
      for (int r2 = 0; r2 < 4; r2++) {
        float sv = s[kc][r2];
        float e = sv * __expf(sv - m_cur);
        pv[kc * 4 + r2] = e;
        ls += fabsf(e);
      }
    ls += __shfl_xor(ls, 16);
    ls += __shfl_xor(ls, 32);
    l_run += ls;

    // P -> fp16, wave-private LDS roundtrip to B-operand layout
#pragma unroll
    for (int kc = 0; kc < 2; kc++) {
      f16x4 p4 = {(f16)pv[kc * 4], (f16)pv[kc * 4 + 1], (f16)pv[kc * 4 + 2],
                  (f16)pv[kc * 4 + 3]};
      *(f16x4*)&p_lds[w][li * 40 + kc * 16 + 4 * g] = p4;
    }
    f16x8 pf = *(const f16x8*)&p_lds[w][li * 40 + 8 * g];

    // acc[c,q] += kvT[c,k] * P^T[k,q]
#pragma unroll
    for (int ct = 0; ct < 16; ct++) {
      int c = ct * 16 + li;
      int ss = g ^ ((c >> 1) & 3);
      f16x8 vf = *(const f16x8*)((const char*)kv_lds + c * 64 + ss * 16);
      acc[ct] = MFMA_F16(vf, pf, acc[ct]);
    }
  }

  // exact fixup to the true max (swishmax is NOT shift invariant: denom has +1)
  float sfix = __expf(m_cur - m_true);
  float invd = sfix / (l_run * sfix + 1.0f);
  f16* orow = vs_c + ((size_t)(bh >> 3) * 2048 + qb * 64 + w * 16 + li) * 2048 + (bh & 7) * 256;
#pragma unroll
  for (int ct = 0; ct < 16; ct++) {
    f16x4 v = {(f16)(acc[ct][0] * invd), (f16)(acc[ct][1] * invd),
               (f16)(acc[ct][2] * invd), (f16)(acc[ct][3] * invd)};
    *(f16x4*)(orow + ct * 16 + 4 * g) = v;
  }
}

// --------------------------- fp16 final GEMM (head-sum in K) -----------------
// M=4096(b,q) K=2048(h,c) N=1024(t). A=vs_c, B=vupT [1024][2048]. out fp32.
__global__ __launch_bounds__(256, 2) void final_gemm(const f16* __restrict__ A,
                                                     const f16* __restrict__ Bm,
                                                     float* __restrict__ outp) {
  __shared__ __attribute__((aligned(16))) f16 sm[2][128 * 32];
  int tid = threadIdx.x, w = tid >> 6, lane = tid & 63, g = lane >> 4, li = lane & 15;
  int mb = blockIdx.y * 128, nb = blockIdx.x * 128;
  int wm = (w >> 1) * 64, wn = (w & 1) * 64;
  f32x4 acc[4][4] = {};
  for (int kb = 0; kb < 2048; kb += 32) {
    __syncthreads();
#pragma unroll
    for (int i = 0; i < 2; i++) {
      int off = (w * 2 + i) * 1024 + lane * 16;
      int row = off >> 6;
      int ss = ((off >> 4) & 3) ^ ((row >> 1) & 3);
      int dst = (w * 2 + i) * 512;
      g2lds16(A + (size_t)(mb + row) * 2048 + kb + ss * 8, &sm[0][dst]);
      g2lds16(Bm + (size_t)(nb + row) * 2048 + kb + ss * 8, &sm[1][dst]);
    }
    __syncthreads();
    f16x8 af[4], bf[4];
#pragma unroll
    for (int f = 0; f < 4; f++) {
      int ra = wm + f * 16 + li;
      int sa = g ^ ((ra >> 1) & 3);
      af[f] = *(const f16x8*)&sm[0][ra * 32 + sa * 8];
      int rb = wn + f * 16 + li;
      int sb = g ^ ((rb >> 1) & 3);
      bf[f] = *(const f16x8*)&sm[1][rb * 32 + sb * 8];
    }
#pragma unroll
    for (int mf = 0; mf < 4; mf++)
#pragma unroll
      for (int nf = 0; nf < 4; nf++)
        acc[mf][nf] = MFMA_F16(af[mf], bf[nf], acc[mf][nf]);
  }
#pragma unroll
  for (int mf = 0; mf < 4; mf++)
#pragma unroll
    for (int nf = 0; nf < 4; nf++)
#pragma unroll
      for (int r = 0; r < 4; r++) {
        int m = mb + wm + mf * 16 + 4 * g + r;
        int n = nb + wn + nf * 16 + li;
        outp[(size_t)m * 1024 + n] = acc[mf][nf][r];
      }
}

// ---------------------------------------------------------------------------
extern "C" void kernel_launch(void* const* d_in, const int* in_sizes, int n_in,
                              void* d_out, int out_size, void* d_ws, size_t ws_size,
                              hipStream_t stream) {
  (void)in_sizes; (void)n_in; (void)out_size; (void)ws_size;
  const float* qtok = (const float*)d_in[0];  // [2,2048,1024]
  const float* ktok = (const float*)d_in[1];  // [2,2048,1024]
  const float* kdw = (const float*)d_in[2];   // [8,1024,64]
  const float* qdw = (const float*)d_in[3];   // [8,1024,64]
  const float* qdb = (const float*)d_in[4];   // [8,1,64]
  const float* vdw = (const float*)d_in[5];   // [8,1024,256]
  const float* vup = (const float*)d_in[6];   // [8,256,1024]

  char* ws = (char*)d_ws;
  size_t off = 0;
  auto take = [&](size_t n) { void* p = ws + off; off += (n + 255) & ~(size_t)255; return p; };

  short* qtok_hi = (short*)take(8u << 20);  // [4096][1024] bf16
  short* qtok_lo = (short*)take(8u << 20);
  short* ktok_hi = (short*)take(8u << 20);
  short* ktok_lo = (short*)take(8u << 20);
  f16* ktok_f = (f16*)take(8u << 20);       // [4096][1024] f16
  short* wqT_hi = (short*)take(1u << 20);   // [512][1024]
  short* wqT_lo = (short*)take(1u << 20);
  short* wkT_hi = (short*)take(1u << 20);
  short* wkT_lo = (short*)take(1u << 20);
  f16* vdT = (f16*)take(4u << 20);          // [2048][1024] f16 (Wv_down^T)
  f16* vuT = (f16*)take(4u << 20);          // [1024][2048] f16 (Wv_up^T)
  short* q_split = (short*)take(8u << 20);  // [16][2048][128] bf16 hi|lo
  short* k_split = (short*)take(8u << 20);
  // Aliased scratch (stream-ordered safe): ktok_hi/lo dead after proj_gemm,
  // qtok_hi/lo dead after proj_gemm. Total ws use = 68MB.
  f16* kvT = (f16*)(void*)ktok_hi;   // 16MB: [16][256][2048]
  f16* vs_c = (f16*)(void*)qtok_hi;  // 16MB: [2][2048][2048]

  ew_split<<<2048, 256, 0, stream>>>(qtok, qtok_hi, qtok_lo, (f16*)nullptr, 1048576);
  ew_split<<<2048, 256, 0, stream>>>(ktok, ktok_hi, ktok_lo, ktok_f, 1048576);
  transpose_split<<<dim3(1, 16, 8), 256, 0, stream>>>(qdw, wqT_hi, wqT_lo, nullptr, 1024, 64);
  transpose_split<<<dim3(1, 16, 8), 256, 0, stream>>>(kdw, wkT_hi, wkT_lo, nullptr, 1024, 64);
  transpose_split<<<dim3(4, 16, 8), 256, 0, stream>>>(vdw, nullptr, nullptr, vdT, 1024, 256);
  transpose_split<<<dim3(16, 32, 1), 256, 0, stream>>>(vup, nullptr, nullptr, vuT, 2048, 1024);

  proj_gemm<<<dim3(4, 32, 2), 256, 0, stream>>>(qtok_hi, qtok_lo, ktok_hi, ktok_lo,
                                                wqT_hi, wqT_lo, wkT_hi, wkT_lo, qdb,
                                                q_split, k_split);
  kv_gemm<<<dim3(16, 32), 256, 0, stream>>>(ktok_f, vdT, kvT);
  flash_attn<<<512, 256, 0, stream>>>(q_split, k_split, kvT, vs_c);
  final_gemm<<<dim3(8, 32), 256, 0, stream>>>(vs_c, vuT, (float*)d_out);
}

// Round 2
// 228.316 us; speedup vs baseline: 1.0660x; 1.0660x over previous
//
#include <hip/hip_runtime.h>
#include <hip/hip_fp16.h>
#include <math.h>

// ---------------------------------------------------------------------------
// AttentionZP: swishmax attention, B=2, H=8, T=1024, A=64, C=256, Q=K=2048.
//
// Pipeline (all on `stream`):
//   1. ew_split:        tokens fp32 -> bf16 hi/lo (+ fp16 copy for key tokens)
//   2. transpose_split: weights fp32 -> transposed bf16 hi/lo (Wq,Wk) / fp16 (Wv_down, Wv_up)
//   3. proj_gemm:       q = Qtok*Wq + bias, k = Ktok*Wk   (split-bf16 3-term MFMA, out hi|lo)
//   4. kv_gemm:         kvT[bh][c][key] = (Ktok*Wv_down)^T (fp16 MFMA)
//   5. flash_attn:      per (b,h,64-q-block): online swishmax over keys, acc = attn^T*kv
//   6. final_gemm:      out[b,q,t] = vs_c[b,q,(h,c)] * vupT[(h,c)->t]  (fp16, head-sum in K)
//
// Round 1 -> 2: all four heavy kernels were single-buffered (load -> vmcnt(0)
// drain -> compute, fully serial). Switched to 2-phase double-buffered LDS
// (T3-minimum): issue tile t+1's global_load_lds before computing tile t, one
// barrier/iter. s_setprio(1) around flash MFMA clusters (T5).
// ---------------------------------------------------------------------------

typedef _Float16 f16;
typedef _Float16 f16x4 __attribute__((ext_vector_type(4)));
typedef _Float16 f16x8 __attribute__((ext_vector_type(8)));
typedef short s16x4 __attribute__((ext_vector_type(4)));
typedef short bf16x8 __attribute__((ext_vector_type(8)));
typedef float f32x4 __attribute__((ext_vector_type(4)));

#define MFMA_F16(a, b, c) __builtin_amdgcn_mfma_f32_16x16x32_f16(a, b, c, 0, 0, 0)
#define MFMA_BF16(a, b, c) __builtin_amdgcn_mfma_f32_16x16x32_bf16(a, b, c, 0, 0, 0)

__device__ __forceinline__ void g2lds16(const void* g, void* l) {
  // async global->LDS, 16B/lane; LDS dest is wave-uniform base + lane*16
  __builtin_amdgcn_global_load_lds((__attribute__((address_space(1))) void*)g,
                                   (__attribute__((address_space(3))) void*)l, 16, 0, 0);
}

__device__ __forceinline__ short f32_bf16(float x) {
  union { float f; unsigned u; } v; v.f = x;
  unsigned r = v.u + 0x7FFFu + ((v.u >> 16) & 1u);  // RTN-even
  return (short)(r >> 16);
}
__device__ __forceinline__ float bf16_f32(short h) {
  union { unsigned u; float f; } v; v.u = ((unsigned)(unsigned short)h) << 16;
  return v.f;
}

// --------------------------- prep: elementwise split ------------------------
__global__ __launch_bounds__(256) void ew_split(const float* __restrict__ in,
                                                short* __restrict__ bhi,
                                                short* __restrict__ blo,
                                                f16* __restrict__ fo, int n4) {
  int i = blockIdx.x * 256 + threadIdx.x;
  int stride = gridDim.x * 256;
  for (; i < n4; i += stride) {
    f32x4 v = ((const f32x4*)in)[i];
    s16x4 h, l;
    f16x4 f;
#pragma unroll
    for (int j = 0; j < 4; j++) {
      short hj = f32_bf16(v[j]);
      h[j] = hj;
      l[j] = f32_bf16(v[j] - bf16_f32(hj));
      f[j] = (f16)v[j];
    }
    ((s16x4*)bhi)[i] = h;
    ((s16x4*)blo)[i] = l;
    if (fo) ((f16x4*)fo)[i] = f;
  }
}

// --------------------------- prep: transpose (+split) -----------------------
// in: [batch][R][C] f32 -> out: [batch][C][R]  (bf16 hi/lo and/or f16)
__global__ __launch_bounds__(256) void transpose_split(const float* __restrict__ in,
                                                       short* __restrict__ bhi,
                                                       short* __restrict__ blo,
                                                       f16* __restrict__ fo,
                                                       int R, int C) {
  __shared__ float t[64][65];
  int cb = blockIdx.x * 64, rb = blockIdx.y * 64;
  size_t batch = (size_t)blockIdx.z * R * C;
  int tid = threadIdx.x;
#pragma unroll
  for (int i = 0; i < 4; i++) {
    int r = (tid >> 4) + i * 16, c4 = (tid & 15) * 4;
    f32x4 v = *(const f32x4*)(in + batch + (size_t)(rb + r) * C + cb + c4);
    t[r][c4] = v[0]; t[r][c4 + 1] = v[1]; t[r][c4 + 2] = v[2]; t[r][c4 + 3] = v[3];
  }
  __syncthreads();
#pragma unroll
  for (int i = 0; i < 4; i++) {
    int c = (tid >> 4) + i * 16, r4 = (tid & 15) * 4;
    float v0 = t[r4][c], v1 = t[r4 + 1][c], v2 = t[r4 + 2][c], v3 = t[r4 + 3][c];
    size_t o = batch + (size_t)(cb + c) * R + rb + r4;
    if (bhi) {
      s16x4 h = {f32_bf16(v0), f32_bf16(v1), f32_bf16(v2), f32_bf16(v3)};
      *(s16x4*)(bhi + o) = h;
      s16x4 l = {f32_bf16(v0 - bf16_f32(h[0])), f32_bf16(v1 - bf16_f32(h[1])),
                 f32_bf16(v2 - bf16_f32(h[2])), f32_bf16(v3 - bf16_f32(h[3]))};
      *(s16x4*)(blo + o) = l;
    }
    if (fo) {
      f16x4 fv = {(f16)v0, (f16)v1, (f16)v2, (f16)v3};
      *(f16x4*)(fo + o) = fv;
    }
  }
}

// --------------------------- split-bf16 projection GEMM ----------------------
// M=4096(b,row) K=1024(t) N=512(h,a).  A=[4096][1024] hi/lo, B(T)=[512][1024] hi/lo.
// out: {q,k}_split[bh][row][ hi(64) | lo(64) ]  (bf16)
__global__ __launch_bounds__(256, 2) void proj_gemm(
    const short* __restrict__ qtok_hi, const short* __restrict__ qtok_lo,
    const short* __restrict__ ktok_hi, const short* __restrict__ ktok_lo,
    const short* __restrict__ wqT_hi, const short* __restrict__ wqT_lo,
    const short* __restrict__ wkT_hi, const short* __restrict__ wkT_lo,
    const float* __restrict__ bias, short* __restrict__ q_split,
    short* __restrict__ k_split) {
  const bool isQ = (blockIdx.z == 0);
  const short* Ahi = isQ ? qtok_hi : ktok_hi;
  const short* Alo = isQ ? qtok_lo : ktok_lo;
  const short* Bhi = isQ ? wqT_hi : wkT_hi;
  const short* Blo = isQ ? wqT_lo : wkT_lo;
  short* outp = isQ ? q_split : k_split;

  __shared__ __attribute__((aligned(16))) short sm[2][4][128 * 32];  // 64KB dbuf

  int tid = threadIdx.x, w = tid >> 6, lane = tid & 63, g = lane >> 4, li = lane & 15;
  int mb = blockIdx.y * 128, nb = blockIdx.x * 128;
  int wm = (w >> 1) * 64, wn = (w & 1) * 64;

  f32x4 acc[4][4] = {};

  auto STAGE = [&](int kb, int buf) {
#pragma unroll
    for (int i = 0; i < 2; i++) {
      int off = (w * 2 + i) * 1024 + lane * 16;  // bytes within 8KB tile
      int row = off >> 6;
      int ss = ((off >> 4) & 3) ^ ((row >> 1) & 3);  // XOR swizzle, 64B rows
      size_t asrc = (size_t)(mb + row) * 1024 + kb + ss * 8;
      size_t bsrc = (size_t)(nb + row) * 1024 + kb + ss * 8;
      int dst = (w * 2 + i) * 512;  // halfs
      g2lds16(Ahi + asrc, &sm[buf][0][dst]);
      g2lds16(Alo + asrc, &sm[buf][1][dst]);
      g2lds16(Bhi + bsrc, &sm[buf][2][dst]);
      g2lds16(Blo + bsrc, &sm[buf][3][dst]);
    }
  };

  STAGE(0, 0);
  __syncthreads();
  for (int kb = 0; kb < 1024; kb += 32) {
    int cur = (kb >> 5) & 1;
    if (kb + 32 < 1024) STAGE(kb + 32, cur ^ 1);
    bf16x8 af[4][2], bf[4][2];
#pragma unroll
    for (int f = 0; f < 4; f++) {
      int ra = wm + f * 16 + li;
      int sa = g ^ ((ra >> 1) & 3);
      af[f][0] = *(const bf16x8*)&sm[cur][0][ra * 32 + sa * 8];
      af[f][1] = *(const bf16x8*)&sm[cur][1][ra * 32 + sa * 8];
      int rb = wn + f * 16 + li;
      int sb = g ^ ((rb >> 1) & 3);
      bf[f][0] = *(const bf16x8*)&sm[cur][2][rb * 32 + sb * 8];
      bf[f][1] = *(const bf16x8*)&sm[cur][3][rb * 32 + sb * 8];
    }
#pragma unroll
    for (int mf = 0; mf < 4; mf++)
#pragma unroll
      for (int nf = 0; nf < 4; nf++) {
        acc[mf][nf] = MFMA_BF16(af[mf][0], bf[nf][0], acc[mf][nf]);
        acc[mf][nf] = MFMA_BF16(af[mf][0], bf[nf][1], acc[mf][nf]);
        acc[mf][nf] = MFMA_BF16(af[mf][1], bf[nf][0], acc[mf][nf]);
      }
    __syncthreads();
  }
#pragma unroll
  for (int mf = 0; mf < 4; mf++)
#pragma unroll
    for (int nf = 0; nf < 4; nf++)
#pragma unroll
      for (int r = 0; r < 4; r++) {
        int m = mb + wm + mf * 16 + 4 * g + r;
        int n = nb + wn + nf * 16 + li;
        float v = acc[mf][nf][r];
        if (isQ) v += bias[n];
        short hi = f32_bf16(v);
        short lo = f32_bf16(v - bf16_f32(hi));
        size_t base = ((size_t)((m >> 11) * 8 + (n >> 6)) * 2048 + (m & 2047)) * 128;
        outp[base + (n & 63)] = hi;
        outp[base + 64 + (n & 63)] = lo;
      }
}

// --------------------------- fp16 kv GEMM (writes kv transposed) ------------
// M=4096(key rows) K=1024(t) N=2048(h,c). out kvT[bh][c][key] f16.
__global__ __launch_bounds__(256, 2) void kv_gemm(const f16* __restrict__ A,
                                                  const f16* __restrict__ Bm,
                                                  f16* __restrict__ kvT) {
  __shared__ __attribute__((aligned(16))) f16 sm[2][2][128 * 32];  // 32KB dbuf
  int tid = threadIdx.x, w = tid >> 6, lane = tid & 63, g = lane >> 4, li = lane & 15;
  int mb = blockIdx.y * 128, nb = blockIdx.x * 128;
  int wm = (w >> 1) * 64, wn = (w & 1) * 64;
  f32x4 acc[4][4] = {};

  auto STAGE = [&](int kb, int buf) {
#pragma unroll
    for (int i = 0; i < 2; i++) {
      int off = (w * 2 + i) * 1024 + lane * 16;
      int row = off >> 6;
      int ss = ((off >> 4) & 3) ^ ((row >> 1) & 3);
      int dst = (w * 2 + i) * 512;
      g2lds16(A + (size_t)(mb + row) * 1024 + kb + ss * 8, &sm[buf][0][dst]);
      g2lds16(Bm + (size_t)(nb + row) * 1024 + kb + ss * 8, &sm[buf][1][dst]);
    }
  };

  STAGE(0, 0);
  __syncthreads();
  for (int kb = 0; kb < 1024; kb += 32) {
    int cur = (kb >> 5) & 1;
    if (kb + 32 < 1024) STAGE(kb + 32, cur ^ 1);
    f16x8 af[4], bf[4];
#pragma unroll
    for (int f = 0; f < 4; f++) {
      int ra = wm + f * 16 + li;
      int sa = g ^ ((ra >> 1) & 3);
      af[f] = *(const f16x8*)&sm[cur][0][ra * 32 + sa * 8];
      int rb = wn + f * 16 + li;
      int sb = g ^ ((rb >> 1) & 3);
      bf[f] = *(const f16x8*)&sm[cur][1][rb * 32 + sb * 8];
    }
#pragma unroll
    for (int mf = 0; mf < 4; mf++)
#pragma unroll
      for (int nf = 0; nf < 4; nf++)
        acc[mf][nf] = MFMA_F16(af[mf], bf[nf], acc[mf][nf]);
    __syncthreads();
  }
#pragma unroll
  for (int mf = 0; mf < 4; mf++)
#pragma unroll
    for (int nf = 0; nf < 4; nf++) {
      int m = mb + wm + mf * 16 + 4 * g;  // 4 consecutive keys in regs 0..3
      int n = nb + wn + nf * 16 + li;     // (h<<8)|c
      f16x4 v = {(f16)acc[mf][nf][0], (f16)acc[mf][nf][1], (f16)acc[mf][nf][2],
                 (f16)acc[mf][nf][3]};
      size_t o = ((size_t)((m >> 11) * 8 + (n >> 8)) * 256 + (n & 255)) * 2048 + (m & 2047);
      *(f16x4*)(kvT + o) = v;
    }
}

// --------------------------- flash swishmax attention ------------------------
// grid 512: XCD-swizzled (bh pair per XCD). Block: 64 q rows, 4 waves x 16 q.
// Double-buffered LDS staging (2-phase): issue tile kt+1 before computing kt.
// Per 32-key tile: S^T[k,q]=mfma(K,Q) split-bf16; online swishmax (deferred max,
// true max tracked); P -> fp16 via wave-private LDS; acc[c,q] += mfma(kvT, P^T).
__global__ __launch_bounds__(256, 2) void flash_attn(const short* __restrict__ q_split,
                                                     const short* __restrict__ k_split,
                                                     const f16* __restrict__ kvT,
                                                     f16* __restrict__ vs_c) {
  __shared__ __attribute__((aligned(16))) short k_lds[2][32 * 128];  // 16KB dbuf
  __shared__ __attribute__((aligned(16))) f16 kv_lds[2][256 * 32];   // 32KB dbuf
  __shared__ __attribute__((aligned(16))) f16 p_lds[4][640];         // wave-private P

  const int bid = blockIdx.x;
  const int bh = ((bid & 7) << 1) + ((bid >> 3) & 1);  // 2 bh per XCD for L2 reuse
  const int qb = bid >> 4;
  const int tid = threadIdx.x;
  const int w = tid >> 6, lane = tid & 63, g = lane >> 4, li = lane & 15;

  // Q fragments (persist whole kernel): B-operand, lane holds its q-row's a-slice
  const short* qrow = q_split + ((size_t)bh * 2048 + qb * 64 + w * 16 + li) * 128;
  bf16x8 qf[2][2];
#pragma unroll
  for (int ach = 0; ach < 2; ach++)
#pragma unroll
    for (int hl = 0; hl < 2; hl++)
      qf[ach][hl] = *(const bf16x8*)(qrow + hl * 64 + ach * 32 + g * 8);

  const short* kbase = k_split + (size_t)bh * 2048 * 128;
  const f16* kvbase = kvT + (size_t)bh * 256 * 2048;

  float m_cur = -INFINITY, m_true = -INFINITY, l_run = 0.f;
  f32x4 acc[16] = {};

  auto STAGE = [&](int kt, int buf) {
    // K tile [32][128] (256B rows, 16 slots, swz slot^(row&7))
#pragma unroll
    for (int i = 0; i < 2; i++) {
      int off = (w * 2 + i) * 1024 + lane * 16;
      int row = off >> 8;
      int ss = ((off >> 4) & 15) ^ (row & 7);
      g2lds16(kbase + (size_t)(kt * 32 + row) * 128 + ss * 8,
              (char*)k_lds[buf] + (w * 2 + i) * 1024);
    }
    // kvT tile [256][32] (64B rows, 4 slots, swz slot^((c>>1)&3))
#pragma unroll
    for (int i = 0; i < 4; i++) {
      int off = (w * 4 + i) * 1024 + lane * 16;
      int c = off >> 6;
      int ss = ((off >> 4) & 3) ^ ((c >> 1) & 3);
      g2lds16(kvbase + (size_t)c * 2048 + kt * 32 + ss * 8,
              (char*)kv_lds[buf] + (w * 4 + i) * 1024);
    }
  };

  STAGE(0, 0);
  __syncthreads();

  for (int kt = 0; kt < 64; kt++) {
    const int cur = kt & 1;
    if (kt < 63) STAGE(kt + 1, cur ^ 1);

    // S^T[k, q] over 32 keys x this wave's 16 q
    f32x4 s[2] = {};
    __builtin_amdgcn_s_setprio(1);
#pragma unroll
    for (int kc = 0; kc < 2; kc++) {
      const int r = kc * 16 + li;
#pragma unroll
      for (int ach = 0; ach < 2; ach++) {
        int sh = (ach * 4 + g) ^ (r & 7);
        int sl = (8 + ach * 4 + g) ^ (r & 7);
        bf16x8 khi = *(const bf16x8*)((const char*)k_lds[cur] + r * 256 + sh * 16);
        bf16x8 klo = *(const bf16x8*)((const char*)k_lds[cur] + r * 256 + sl * 16);
        s[kc] = MFMA_BF16(khi, qf[ach][0], s[kc]);
        s[kc] = MFMA_BF16(khi, qf[ach][1], s[kc]);
        s[kc] = MFMA_BF16(klo, qf[ach][0], s[kc]);
      }
    }
    __builtin_amdgcn_s_setprio(0);

    // online swishmax; lane's q = li, its 8 S values span 8 keys
    float tmax = fmaxf(fmaxf(fmaxf(s[0][0], s[0][1]), fmaxf(s[0][2], s[0][3])),
                       fmaxf(fmaxf(s[1][0], s[1][1]), fmaxf(s[1][2], s[1][3])));
    tmax = fmaxf(tmax, __shfl_xor(tmax, 16));
    tmax = fmaxf(tmax, __shfl_xor(tmax, 32));
    m_true = fmaxf(m_true, tmax);
    if (__any(tmax > m_cur + 4.0f)) {  // deferred rescale; P bounded by ~117*e^4 < f16 max
      float mn = fmaxf(m_cur, tmax);
      float sc = __expf(m_cur - mn);  // first iter: exp(-inf)=0, acc already 0
      l_run *= sc;
#pragma unroll
      for (int i = 0; i < 16; i++) acc[i] *= sc;
      m_cur = mn;
    }
    float ls = 0.f;
    float pv[8];
#pragma unroll
    for (int kc = 0; kc < 2; kc++)
#pragma unroll
      for (int r2 = 0; r2 < 4; r2++) {
        float sv = s[kc][r2];
        float e = sv * __expf(sv - m_cur);
        pv[kc * 4 + r2] = e;
        ls += fabsf(e);
      }
    ls += __shfl_xor(ls, 16);
    ls += __shfl_xor(ls, 32);
    l_run += ls;

    // P -> fp16, wave-private LDS roundtrip to B-operand layout
#pragma unroll
    for (int kc = 0; kc < 2; kc++) {
      f16x4 p4 = {(f16)pv[kc * 4], (f16)pv[kc * 4 + 1], (f16)pv[kc * 4 + 2],
                  (f16)pv[kc * 4 + 3]};
      *(f16x4*)&p_lds[w][li * 40 + kc * 16 + 4 * g] = p4;
    }
    f16x8 pf = *(const f16x8*)&p_lds[w][li * 40 + 8 * g];

    // acc[c,q] += kvT[c,k] * P^T[k,q]
    __builtin_amdgcn_s_setprio(1);
#pragma unroll
    for (int ct = 0; ct < 16; ct++) {
      int c = ct * 16 + li;
      int ss = g ^ ((c >> 1) & 3);
      f16x8 vf = *(const f16x8*)((const char*)kv_lds[cur] + c * 64 + ss * 16);
      acc[ct] = MFMA_F16(vf, pf, acc[ct]);
    }
    __builtin_amdgcn_s_setprio(0);

    __syncthreads();  // drains vmcnt(0): next tile's loads landed; buf reads done
  }

  // exact fixup to the true max (swishmax is NOT shift invariant: denom has +1)
  float sfix = __expf(m_cur - m_true);
  float invd = sfix / (l_run * sfix + 1.0f);
  f16* orow = vs_c + ((size_t)(bh >> 3) * 2048 + qb * 64 + w * 16 + li) * 2048 + (bh & 7) * 256;
#pragma unroll
  for (int ct = 0; ct < 16; ct++) {
    f16x4 v = {(f16)(acc[ct][0] * invd), (f16)(acc[ct][1] * invd),
               (f16)(acc[ct][2] * invd), (f16)(acc[ct][3] * invd)};
    *(f16x4*)(orow + ct * 16 + 4 * g) = v;
  }
}

// --------------------------- fp16 final GEMM (head-sum in K) -----------------
// M=4096(b,q) K=2048(h,c) N=1024(t). A=vs_c, B=vupT [1024][2048]. out fp32.
__global__ __launch_bounds__(256, 2) void final_gemm(const f16* __restrict__ A,
                                                     const f16* __restrict__ Bm,
                                                     float* __restrict__ outp) {
  __shared__ __attribute__((aligned(16))) f16 sm[2][2][128 * 32];  // 32KB dbuf
  int tid = threadIdx.x, w = tid >> 6, lane = tid & 63, g = lane >> 4, li = lane & 15;
  int mb = blockIdx.y * 128, nb = blockIdx.x * 128;
  int wm = (w >> 1) * 64, wn = (w & 1) * 64;
  f32x4 acc[4][4] = {};

  auto STAGE = [&](int kb, int buf) {
#pragma unroll
    for (int i = 0; i < 2; i++) {
      int off = (w * 2 + i) * 1024 + lane * 16;
      int row = off >> 6;
      int ss = ((off >> 4) & 3) ^ ((row >> 1) & 3);
      int dst = (w * 2 + i) * 512;
      g2lds16(A + (size_t)(mb + row) * 2048 + kb + ss * 8, &sm[buf][0][dst]);
      g2lds16(Bm + (size_t)(nb + row) * 2048 + kb + ss * 8, &sm[buf][1][dst]);
    }
  };

  STAGE(0, 0);
  __syncthreads();
  for (int kb = 0; kb < 2048; kb += 32) {
    int cur = (kb >> 5) & 1;
    if (kb + 32 < 2048) STAGE(kb + 32, cur ^ 1);
    f16x8 af[4], bf[4];
#pragma unroll
    for (int f = 0; f < 4; f++) {
      int ra = wm + f * 16 + li;
      int sa = g ^ ((ra >> 1) & 3);
      af[f] = *(const f16x8*)&sm[cur][0][ra * 32 + sa * 8];
      int rb = wn + f * 16 + li;
      int sb = g ^ ((rb >> 1) & 3);
      bf[f] = *(const f16x8*)&sm[cur][1][rb * 32 + sb * 8];
    }
#pragma unroll
    for (int mf = 0; mf < 4; mf++)
#pragma unroll
      for (int nf = 0; nf < 4; nf++)
        acc[mf][nf] = MFMA_F16(af[mf], bf[nf], acc[mf][nf]);
    __syncthreads();
  }
#pragma unroll
  for (int mf = 0; mf < 4; mf++)
#pragma unroll
    for (int nf = 0; nf < 4; nf++)
#pragma unroll
      for (int r = 0; r < 4; r++) {
        int m = mb + wm + mf * 16 + 4 * g + r;
        int n = nb + wn + nf * 16 + li;
        outp[(size_t)m * 1024 + n] = acc[mf][nf][r];
      }
}

// ---------------------------------------------------------------------------
extern "C" void kernel_launch(void* const* d_in, const int* in_sizes, int n_in,
                              void* d_out, int out_size, void* d_ws, size_t ws_size,
                              hipStream_t stream) {
  (void)in_sizes; (void)n_in; (void)out_size; (void)ws_size;
  const float* qtok = (const float*)d_in[0];  // [2,2048,1024]
  const float* ktok = (const float*)d_in[1];  // [2,2048,1024]
  const float* kdw = (const float*)d_in[2];   // [8,1024,64]
  const float* qdw = (const float*)d_in[3];   // [8,1024,64]
  const float* qdb = (const float*)d_in[4];   // [8,1,64]
  const float* vdw = (const float*)d_in[5];   // [8,1024,256]
  const float* vup = (const float*)d_in[6];   // [8,256,1024]

  char* ws = (char*)d_ws;
  size_t off = 0;
  auto take = [&](size_t n) { void* p = ws + off; off += (n + 255) & ~(size_t)255; return p; };

  short* qtok_hi = (short*)take(8u << 20);  // [4096][1024] bf16
  short* qtok_lo = (short*)take(8u << 20);
  short* ktok_hi = (short*)take(8u << 20);
  short* ktok_lo = (short*)take(8u << 20);
  f16* ktok_f = (f16*)take(8u << 20);       // [4096][1024] f16
  short* wqT_hi = (short*)take(1u << 20);   // [512][1024]
  short* wqT_lo = (short*)take(1u << 20);
  short* wkT_hi = (short*)take(1u << 20);
  short* wkT_lo = (short*)take(1u << 20);
  f16* vdT = (f16*)take(4u << 20);          // [2048][1024] f16 (Wv_down^T)
  f16* vuT = (f16*)take(4u << 20);          // [1024][2048] f16 (Wv_up^T)
  short* q_split = (short*)take(8u << 20);  // [16][2048][128] bf16 hi|lo
  short* k_split = (short*)take(8u << 20);
  // Aliased scratch (stream-ordered safe): ktok_hi/lo dead after proj_gemm,
  // qtok_hi/lo dead after proj_gemm. Total ws use = 68MB.
  f16* kvT = (f16*)(void*)ktok_hi;   // 16MB: [16][256][2048]
  f16* vs_c = (f16*)(void*)qtok_hi;  // 16MB: [2][2048][2048]

  ew_split<<<2048, 256, 0, stream>>>(qtok, qtok_hi, qtok_lo, (f16*)nullptr, 1048576);
  ew_split<<<2048, 256, 0, stream>>>(ktok, ktok_hi, ktok_lo, ktok_f, 1048576);
  transpose_split<<<dim3(1, 16, 8), 256, 0, stream>>>(qdw, wqT_hi, wqT_lo, nullptr, 1024, 64);
  transpose_split<<<dim3(1, 16, 8), 256, 0, stream>>>(kdw, wkT_hi, wkT_lo, nullptr, 1024, 64);
  transpose_split<<<dim3(4, 16, 8), 256, 0, stream>>>(vdw, nullptr, nullptr, vdT, 1024, 256);
  transpose_split<<<dim3(16, 32, 1), 256, 0, stream>>>(vup, nullptr, nullptr, vuT, 2048, 1024);

  proj_gemm<<<dim3(4, 32, 2), 256, 0, stream>>>(qtok_hi, qtok_lo, ktok_hi, ktok_lo,
                                                wqT_hi, wqT_lo, wkT_hi, wkT_lo, qdb,
                                                q_split, k_split);
  kv_gemm<<<dim3(16, 32), 256, 0, stream>>>(ktok_f, vdT, kvT);
  flash_attn<<<512, 256, 0, stream>>>(q_split, k_split, kvT, vs_c);
  final_gemm<<<dim3(8, 32), 256, 0, stream>>>(vs_c, vuT, (float*)d_out);
}